// Round 10
// baseline (604.906 us; speedup 1.0000x reference)
//
#include <hip/hip_runtime.h>

// VQ-VAE codebook quantization — R10: two-kernel, sequential-stream writer.
// x: (4096, 1024) f32; codebook: (128, 256, 8) f32.
// out = [cw_embed (4096*1024 f32) | one_hot (4096*128*256 f32)].
//
// R9 post-mortem: LDS-amortization regressed -> screen isn't the limiter;
// store-stream parallelism + cached stores are what won in R8. Remaining
// ~50us over the 91us floor pinned on DRAM row locality: fused-per-c waves
// stride 128KB between 1KB bursts (structural — c fixed per block). R10
// tests the fix: K1 (R8 screen+fp64 repair, byte-identical numerics) emits
// idx only; K2 writes pair-linear — each wave streams 64KB of CONSECUTIVE
// one-hot rows with cached stores. If this doesn't beat R8's 582, strided
// bursts aren't the issue and R8 is the plateau.

constexpr int B_  = 4096;
constexpr int C_  = 128;
constexpr int K_  = 256;
constexpr int D_  = 8;
constexpr int TPB = 256;
constexpr int NP  = B_ * C_;   // 524288 pairs

constexpr int   BPT   = 4;           // pairs per thread in K1
constexpr int   BTILE = TPB * BPT;   // 1024 b per block
constexpr float TAU2  = 1.0e-3f;     // ambiguity gap threshold

typedef float vf4 __attribute__((ext_vector_type(4)));

// ---------------- K1: fp32 top-2 screen + inline fp64 repair -> idx ----------------
__global__ __launch_bounds__(TPB) void vq_screen_fix(
    const float* __restrict__ x,
    const float* __restrict__ cb,
    int* __restrict__ idx_out)
{
    __shared__ float s_cbf[K_ * D_];  // 8 KB fp32 codebook slice
    __shared__ float s_c2f[K_];       // 1 KB fp32 ||c_k||^2

    const int c    = blockIdx.x;   // 0..127
    const int bt   = blockIdx.y;   // 0..3
    const int tid  = threadIdx.x;
    const int lane = tid & 63;

    {
        const float4* gcb = (const float4*)(cb + (size_t)c * (K_ * D_));
        ((float4*)s_cbf)[tid]       = gcb[tid];
        ((float4*)s_cbf)[tid + TPB] = gcb[tid + TPB];
    }
    __syncthreads();
    {
        const float* v = s_cbf + tid * D_;
        float s = 0.f;
        #pragma unroll
        for (int d = 0; d < D_; ++d) s = fmaf(v[d], v[d], s);
        s_c2f[tid] = s;
    }
    __syncthreads();

    const float4* scb4 = (const float4*)s_cbf;
    const int bbase = bt * BTILE;

    float xf[BPT][D_];
    #pragma unroll
    for (int j = 0; j < BPT; ++j) {
        const int b = bbase + j * TPB + tid;
        const float4* xp = (const float4*)(x + (size_t)b * (C_ * D_) + c * D_);
        const float4 a = xp[0];
        const float4 h = xp[1];
        xf[j][0] = a.x; xf[j][1] = a.y; xf[j][2] = a.z; xf[j][3] = a.w;
        xf[j][4] = h.x; xf[j][5] = h.y; xf[j][6] = h.z; xf[j][7] = h.w;
    }

    float s1[BPT], s2[BPT];
    int   k1[BPT];
    #pragma unroll
    for (int j = 0; j < BPT; ++j) { s1[j] = 3.4e38f; s2[j] = 3.4e38f; k1[j] = 0; }

    #pragma unroll 2
    for (int k = 0; k < K_; ++k) {
        const float4 clo = scb4[k * 2];
        const float4 chi = scb4[k * 2 + 1];
        const float  c2k = s_c2f[k];
        #pragma unroll
        for (int j = 0; j < BPT; ++j) {
            float dot = xf[j][0] * clo.x;
            dot = fmaf(xf[j][1], clo.y, dot);
            dot = fmaf(xf[j][2], clo.z, dot);
            dot = fmaf(xf[j][3], clo.w, dot);
            dot = fmaf(xf[j][4], chi.x, dot);
            dot = fmaf(xf[j][5], chi.y, dot);
            dot = fmaf(xf[j][6], chi.z, dot);
            dot = fmaf(xf[j][7], chi.w, dot);
            const float score = fmaf(-2.f, dot, c2k);
            // top-2 (s2 uses OLD s1; strict < keeps first-index winner)
            s2[j] = fminf(s2[j], fmaxf(score, s1[j]));
            const bool lt = score < s1[j];
            k1[j] = lt ? k : k1[j];
            s1[j] = lt ? score : s1[j];
        }
    }

    // inline fp64 repair of ambiguous pairs (wave-cooperative);
    // (double)f32 from LDS == R2's exact staging -> argmin matches np.
    #pragma unroll
    for (int j = 0; j < BPT; ++j) {
        const bool amb = (s2[j] - s1[j]) <= TAU2;
        unsigned long long mask = __ballot(amb);
        while (mask) {
            const int src = (int)__ffsll((long long)mask) - 1;
            mask &= mask - 1;
            double xd[D_];
            #pragma unroll
            for (int d = 0; d < D_; ++d) xd[d] = (double)__shfl(xf[j][d], src);
            double best = 1.0e300;
            int    bk   = 0;
            #pragma unroll
            for (int t = 0; t < 4; ++t) {
                const int k = lane * 4 + t;      // ascending k within lane
                const float* cv = s_cbf + k * D_;
                double cd[D_];
                #pragma unroll
                for (int d = 0; d < D_; ++d) cd[d] = (double)cv[d];
                double c2k = 0.0;
                #pragma unroll
                for (int d = 0; d < D_; ++d) c2k = fma(cd[d], cd[d], c2k);
                double dot = xd[0] * cd[0];
                #pragma unroll
                for (int d = 1; d < D_; ++d) dot = fma(xd[d], cd[d], dot);
                const double score = fma(-2.0, dot, c2k);
                if (score < best) { best = score; bk = k; }  // first-min
            }
            #pragma unroll
            for (int off = 32; off >= 1; off >>= 1) {
                const double ob  = __shfl_down(best, off);
                const int    obk = __shfl_down(bk,   off);
                if (ob < best) { best = ob; bk = obk; }  // tie -> lower k
            }
            const int win = __shfl(bk, 0);
            if (lane == src) k1[j] = win;
        }
    }

    #pragma unroll
    for (int j = 0; j < BPT; ++j) {
        const int b = bbase + j * TPB + tid;
        idx_out[(size_t)b * C_ + c] = k1[j];
    }
}

// ---------------- K2: sequential-stream writer (cached stores) ----------------
// Pair-linear: each wave writes 64 CONSECUTIVE one-hot rows = one 64KB
// sequential stream (16 full lines per store instr, rows adjacent).
constexpr int GRID2 = 2048;
constexpr int RPB   = NP / GRID2;  // 256 rows per block (4 waves x 64 rows)

__global__ __launch_bounds__(TPB, 4) void vq_write(
    const int*   __restrict__ idx,
    const float* __restrict__ cb,
    float* __restrict__ out_embed,
    float* __restrict__ out_onehot)
{
    const int tid  = threadIdx.x;
    const int lane = tid & 63;
    const int wave = tid >> 6;
    const int blk  = blockIdx.x;

    // one-hot: rows rowbase..rowbase+63 — consecutive 1KB rows per wave
    const int rowbase = blk * RPB + wave * 64;
    const int myk = idx[rowbase + lane];     // one coalesced load per wave
    const int e0 = lane * 4;
    #pragma unroll 8
    for (int i = 0; i < 64; ++i) {
        const int k = __builtin_amdgcn_readlane(myk, i);
        vf4 v;
        v.x = (k == e0    ) ? 1.f : 0.f;
        v.y = (k == e0 + 1) ? 1.f : 0.f;
        v.z = (k == e0 + 2) ? 1.f : 0.f;
        v.w = (k == e0 + 3) ? 1.f : 0.f;
        ((vf4*)(out_onehot + (size_t)(rowbase + i) * K_))[lane] = v;
    }

    // embed: 256 consecutive pairs per block = 512 float4, fully sequential
    const size_t pbase = (size_t)blk * RPB;
    #pragma unroll
    for (int i = 0; i < 2; ++i) {
        const int    f    = i * TPB + tid;   // 0..511
        const int    pl   = f >> 1;
        const int    half = f & 1;
        const size_t pair = pbase + pl;
        const int    c    = (int)(pair & (C_ - 1));
        const int    k    = idx[pair];
        const vf4 val = ((const vf4*)(cb + ((size_t)c * K_ + k) * D_))[half];
        ((vf4*)(out_embed + pbase * D_))[f] = val;
    }
}

extern "C" void kernel_launch(void* const* d_in, const int* in_sizes, int n_in,
                              void* d_out, int out_size, void* d_ws, size_t ws_size,
                              hipStream_t stream) {
    const float* x  = (const float*)d_in[0];
    const float* cb = (const float*)d_in[1];
    float* out        = (float*)d_out;
    float* out_embed  = out;                          // 4096*1024
    float* out_onehot = out + (size_t)B_ * C_ * D_;   // 4096*128*256
    int*   idx_ws     = (int*)d_ws;                   // 524288 ints = 2 MB

    dim3 grid1(C_, B_ / BTILE);  // (128, 4) = 512 blocks
    vq_screen_fix<<<grid1, TPB, 0, stream>>>(x, cb, idx_ws);

    vq_write<<<GRID2, TPB, 0, stream>>>(idx_ws, cb, out_embed, out_onehot);
}

// Round 11
// 587.800 us; speedup vs baseline: 1.0291x; 1.0291x over previous
//
#include <hip/hip_runtime.h>

// VQ-VAE codebook quantization — R11: R8 + per-j compute/store interleave.
// x: (4096, 1024) f32; codebook: (128, 256, 8) f32.
// out = [cw_embed (4096*1024 f32) | one_hot (4096*128*256 f32)].
//
// R10 post-mortem: sequential-stream writer regressed -> DRAM-row theory
// dead; fusion overlap is what matters (R8=582 best). R8's residual ~50us
// over the write floor = intra-block phase serialization: full screen
// (~35us, grid-synchronized) runs before ANY store issues. R11 pipelines
// per-j: screen(j0)->repair(j0)->stores(j0)->screen(j1)->..., so j1 compute
// hides under j0's drain and first stores issue ~2x earlier. All numerics
// and store patterns byte-identical to R8 (absmax 0.0 since R2).

constexpr int B_  = 4096;
constexpr int C_  = 128;
constexpr int K_  = 256;
constexpr int D_  = 8;
constexpr int TPB = 256;

constexpr int   BPT   = 2;           // pairs per thread (2 pipeline stages)
constexpr int   BTILE = TPB * BPT;   // 512 b per block
constexpr float TAU2  = 1.0e-3f;     // ambiguity gap threshold

typedef float vf4 __attribute__((ext_vector_type(4)));

__global__ __launch_bounds__(TPB) void vq_fused(
    const float* __restrict__ x,
    const float* __restrict__ cb,
    float* __restrict__ out_embed,
    float* __restrict__ out_onehot)
{
    __shared__ float s_cbf[K_ * D_];  // 8 KB fp32 codebook slice
    __shared__ float s_c2f[K_];       // 1 KB fp32 ||c_k||^2

    const int c    = blockIdx.x;   // 0..127
    const int bt   = blockIdx.y;   // 0..7
    const int tid  = threadIdx.x;
    const int lane = tid & 63;
    const int wave = tid >> 6;

    // ---- stage codebook slice + c2 ----
    {
        const float4* gcb = (const float4*)(cb + (size_t)c * (K_ * D_));
        ((float4*)s_cbf)[tid]       = gcb[tid];
        ((float4*)s_cbf)[tid + TPB] = gcb[tid + TPB];
    }
    __syncthreads();
    {
        const float* v = s_cbf + tid * D_;
        float s = 0.f;
        #pragma unroll
        for (int d = 0; d < D_; ++d) s = fmaf(v[d], v[d], s);
        s_c2f[tid] = s;
    }
    __syncthreads();
    // LDS read-only below — no more barriers.

    const float4* scb4 = (const float4*)s_cbf;
    const int bbase = bt * BTILE;

    for (int j = 0; j < BPT; ++j) {   // per-j pipeline: compute j, store j
        const int b = bbase + j * TPB + tid;

        // ---- x fragment ----
        float xf[D_];
        {
            const float4* xp = (const float4*)(x + (size_t)b * (C_ * D_) + c * D_);
            const float4 a = xp[0];
            const float4 h = xp[1];
            xf[0] = a.x; xf[1] = a.y; xf[2] = a.z; xf[3] = a.w;
            xf[4] = h.x; xf[5] = h.y; xf[6] = h.z; xf[7] = h.w;
        }

        // ---- fp32 top-2 screen ----
        float s1 = 3.4e38f, s2 = 3.4e38f;
        int   k1 = 0;
        #pragma unroll 4
        for (int k = 0; k < K_; ++k) {
            const float4 clo = scb4[k * 2];
            const float4 chi = scb4[k * 2 + 1];
            const float  c2k = s_c2f[k];
            float dot = xf[0] * clo.x;
            dot = fmaf(xf[1], clo.y, dot);
            dot = fmaf(xf[2], clo.z, dot);
            dot = fmaf(xf[3], clo.w, dot);
            dot = fmaf(xf[4], chi.x, dot);
            dot = fmaf(xf[5], chi.y, dot);
            dot = fmaf(xf[6], chi.z, dot);
            dot = fmaf(xf[7], chi.w, dot);
            const float score = fmaf(-2.f, dot, c2k);
            // top-2 (s2 uses OLD s1; strict < keeps first-index winner)
            s2 = fminf(s2, fmaxf(score, s1));
            const bool lt = score < s1;
            k1 = lt ? k : k1;
            s1 = lt ? score : s1;
        }

        // ---- inline fp64 repair of ambiguous pairs (wave-cooperative) ----
        // (double)f32 from LDS == R2's exact staging -> argmin matches np.
        {
            const bool amb = (s2 - s1) <= TAU2;
            unsigned long long mask = __ballot(amb);
            while (mask) {
                const int src = (int)__ffsll((long long)mask) - 1;
                mask &= mask - 1;
                double xd[D_];
                #pragma unroll
                for (int d = 0; d < D_; ++d) xd[d] = (double)__shfl(xf[d], src);
                double best = 1.0e300;
                int    bk   = 0;
                #pragma unroll
                for (int t = 0; t < 4; ++t) {
                    const int k = lane * 4 + t;      // ascending k within lane
                    const float* cv = s_cbf + k * D_;
                    double cd[D_];
                    #pragma unroll
                    for (int d = 0; d < D_; ++d) cd[d] = (double)cv[d];
                    double c2k = 0.0;
                    #pragma unroll
                    for (int d = 0; d < D_; ++d) c2k = fma(cd[d], cd[d], c2k);
                    double dot = xd[0] * cd[0];
                    #pragma unroll
                    for (int d = 1; d < D_; ++d) dot = fma(xd[d], cd[d], dot);
                    const double score = fma(-2.0, dot, c2k);
                    if (score < best) { best = score; bk = k; }  // first-min
                }
                #pragma unroll
                for (int off = 32; off >= 1; off >>= 1) {
                    const double ob  = __shfl_down(best, off);
                    const int    obk = __shfl_down(bk,   off);
                    if (ob < best) { best = ob; bk = obk; }  // tie -> lower k
                }
                const int win = __shfl(bk, 0);
                if (lane == src) k1 = win;
            }
        }

        // ---- writes for this j (cached; issue and continue to next j) ----
        {
            // embed: own pair, 32B from LDS slice; L2 merges half-lines.
            const size_t pair = (size_t)b * C_ + c;
            float4* dst = (float4*)(out_embed + pair * D_);
            dst[0] = ((const float4*)s_cbf)[k1 * 2];
            dst[1] = ((const float4*)s_cbf)[k1 * 2 + 1];

            // one-hot: wave writes its 64 lanes' rows; 1KB burst per instr.
            const int bw = bbase + j * TPB + wave * 64;
            const int e0 = lane * 4;
            #pragma unroll 8
            for (int i = 0; i < 64; ++i) {
                const int k = __builtin_amdgcn_readlane(k1, i);
                vf4 v;
                v.x = (k == e0    ) ? 1.f : 0.f;
                v.y = (k == e0 + 1) ? 1.f : 0.f;
                v.z = (k == e0 + 2) ? 1.f : 0.f;
                v.w = (k == e0 + 3) ? 1.f : 0.f;
                const size_t row = (size_t)(bw + i) * C_ + c;
                ((vf4*)(out_onehot + row * K_))[lane] = v;
            }
        }
    }
}

extern "C" void kernel_launch(void* const* d_in, const int* in_sizes, int n_in,
                              void* d_out, int out_size, void* d_ws, size_t ws_size,
                              hipStream_t stream) {
    const float* x  = (const float*)d_in[0];
    const float* cb = (const float*)d_in[1];
    float* out        = (float*)d_out;
    float* out_embed  = out;                          // 4096*1024
    float* out_onehot = out + (size_t)B_ * C_ * D_;   // 4096*128*256

    dim3 grid(C_, B_ / BTILE);  // (128, 8) = 1024 blocks, 4 per CU
    vq_fused<<<grid, TPB, 0, stream>>>(x, cb, out_embed, out_onehot);
}